// Round 8
// baseline (556.139 us; speedup 1.0000x reference)
//
#include <hip/hip_runtime.h>

// MiniSelfAttention: B=8, T=2048, D=1024, fp32 in/out, fp16 MFMA internally.
// R8: latency attack. (a) 3-stage LDS ring, prefetch distance 2, partial
// s_waitcnt vmcnt(4) at iter end (newest stage stays in flight — DMA gets ~2
// iter bodies to land instead of <1). (b) XCD-aware block swizzle: all
// col-blocks of a row-panel (S/PV: a whole batch) on one XCD -> panels stay
// hot in that XCD's 4MB L2. XOR bank swizzle kept from R7 (conflicts = 0).
// Tile: 128x128, 4 waves of 64x64 (4x4 frags), 48 KB LDS -> 3 blocks/CU.
//
// ws layout (MB):
//   [0,6)    WqkvT = WqT|WkT|WvT contiguous (fp16 [3072][1024])
//   [6,8)    WpT fp16
//   [8,40)   q fp16 [8][2048][1024]   (later overwritten by ctx)
//   [40,72)  k fp16
//   [72,104) vT fp16 [8][1024][2048]
//   [104,136) x16 fp16 (dead after QKV), overlaid by:
//   [104,168) S fp16 [8][2048][2048]  (softmaxed in place -> P)

typedef _Float16 half_t;
typedef _Float16 half8 __attribute__((ext_vector_type(8)));
typedef float floatx4 __attribute__((ext_vector_type(4)));

// async global->LDS, 16B per lane; LDS dest = wave-uniform base + lane*16
#define GLD16(gp, lp)                                                          \
    __builtin_amdgcn_global_load_lds(                                          \
        (const __attribute__((address_space(1))) void*)(gp),                   \
        (__attribute__((address_space(3))) void*)(lp), 16, 0, 0)

#define WAIT_VM(N)  asm volatile("s_waitcnt vmcnt(" #N ")" ::: "memory")
#define BARRIER()   do { asm volatile("" ::: "memory");                        \
                         __builtin_amdgcn_s_barrier();                         \
                         asm volatile("" ::: "memory"); } while (0)

// ---------------------------------------------------------------------------
// fp16 NT GEMM: 128x128 tile, BK=32, 4 waves (64x64, 4x4 frags),
// 3-stage LDS ring + raw-barrier pipeline + XOR bank swizzle + XCD swizzle.
// EPI: 0 = fp16 C store; 1 = fp32 C + bias; 2 = QKV-routed (q*1/32, k, vT)
// ---------------------------------------------------------------------------
template<int EPI>
__global__ __launch_bounds__(256, 4)
void gemm16(const half_t* __restrict__ A, const half_t* __restrict__ B,
            void* __restrict__ Cv, void* __restrict__ C2, void* __restrict__ C3,
            const float* __restrict__ bias, int K, int lda, int ldb, int ldc,
            long long bsA, long long bsB, long long bsC)
{
    __shared__ half_t As[3 * 128 * 32];  // 24 KB: 3-stage ring, unpadded
    __shared__ half_t Bs[3 * 128 * 32];  // 24 KB

    // ---- XCD swizzle: colocate all col-blocks of a row-panel on one XCD.
    // Assumes round-robin linear-id -> XCD dispatch (perf heuristic only).
    const int gx = gridDim.x, gy = gridDim.y;
    const int lin  = blockIdx.x + gx * (blockIdx.y + gy * blockIdx.z);
    const int xcd  = lin & 7;
    const int slot = lin >> 3;
    const int ppx  = (gy * gridDim.z) >> 3;      // panels per XCD (gy*gz % 8 == 0)
    const int gp   = xcd * ppx + slot / gx;      // global panel
    const int bx   = slot % gx;
    const int by   = gp % gy;
    const long long z = gp / gy;

    const int tid  = threadIdx.x;
    const int lane = tid & 63;
    const int wid  = tid >> 6;           // 0..3
    const int wr   = (wid >> 1) * 64;    // wave grid 2x2
    const int wc   = (wid & 1) * 64;
    const int rowBase = by * 128;
    const int colBase = bx * 128;

    // staging: wave w stages tile rows [w*32, w*32+32) of A and B,
    // two 1KB global_load_lds each. XOR swizzle: lane stages global chunk
    // (lane&3)^((lane>>3)&3) so LDS slot (r, sc) holds chunk sc^((r>>1)&3).
    const int lrow = lane >> 2;                              // 0..15
    const int scol = (((lane & 3) ^ ((lane >> 3) & 3))) * 8; // swizzled chunk

    const half_t* ga0 = A + z * bsA + (long long)(rowBase + wid * 32 + lrow) * lda + scol;
    const half_t* ga1 = ga0 + 16LL * lda;
    const half_t* gb0 = B + z * bsB + (long long)(colBase + wid * 32 + lrow) * ldb + scol;
    const half_t* gb1 = gb0 + 16LL * ldb;
    const int lso0 = (wid * 32) * 32;        // wave-uniform LDS offsets (halves)
    const int lso1 = (wid * 32 + 16) * 32;

    floatx4 acc[4][4];
    #pragma unroll
    for (int m = 0; m < 4; ++m)
        #pragma unroll
        for (int n = 0; n < 4; ++n)
            #pragma unroll
            for (int j = 0; j < 4; ++j) acc[m][n][j] = 0.0f;

    const int fr  = lane & 15;
    // read-side XOR swizzle: global chunk q lives at LDS chunk q^((fr>>1)&3)
    const int fks = (((lane >> 4) ^ ((lane >> 1) & 3))) * 8;
    const int nIter = K >> 5;

    // prolog: tiles 0,1 into ring slots 0,1 (4 GLD16 per wave per tile)
    GLD16(ga0, &As[0 * 4096 + lso0]);
    GLD16(ga1, &As[0 * 4096 + lso1]);
    GLD16(gb0, &Bs[0 * 4096 + lso0]);
    GLD16(gb1, &Bs[0 * 4096 + lso1]);
    GLD16(ga0 + 32, &As[1 * 4096 + lso0]);
    GLD16(ga1 + 32, &As[1 * 4096 + lso1]);
    GLD16(gb0 + 32, &Bs[1 * 4096 + lso0]);
    GLD16(gb1 + 32, &Bs[1 * 4096 + lso1]);
    WAIT_VM(4);          // tile 0 landed; tile 1 still in flight
    BARRIER();

    int cur = 0;         // ring slot of tile 'it'
    for (int it = 0; it < nIter; ++it) {
        // prefetch tile it+2 into slot (cur+2)%3 — readers of that slot
        // retired before the barrier we just passed.
        if (it + 2 < nIter) {
            int pf = cur + 2; if (pf >= 3) pf -= 3;
            const int kk = (it + 2) << 5;
            GLD16(ga0 + kk, &As[pf * 4096 + lso0]);
            GLD16(ga1 + kk, &As[pf * 4096 + lso1]);
            GLD16(gb0 + kk, &Bs[pf * 4096 + lso0]);
            GLD16(gb1 + kk, &Bs[pf * 4096 + lso1]);
        }

        const int co = cur * 4096;
        half8 af[4], bf[4];
        #pragma unroll
        for (int m = 0; m < 4; ++m)
            af[m] = *(const half8*)&As[co + (wr + m * 16 + fr) * 32 + fks];
        #pragma unroll
        for (int n = 0; n < 4; ++n)
            bf[n] = *(const half8*)&Bs[co + (wc + n * 16 + fr) * 32 + fks];
        #pragma unroll
        for (int m = 0; m < 4; ++m)
            #pragma unroll
            for (int n = 0; n < 4; ++n)
                acc[m][n] = __builtin_amdgcn_mfma_f32_16x16x32_f16(af[m], bf[n], acc[m][n], 0, 0, 0);

        // publish tile it+1: wait only until its 4 loads landed (leave the
        // newest stage in flight), then barrier. No full drain until tail.
        if (it + 1 < nIter) {
            if (it + 2 < nIter) { WAIT_VM(4); } else { WAIT_VM(0); }
            BARRIER();
        }
        ++cur; if (cur >= 3) cur = 0;
    }

    // epilogue: C/D layout col=lane&15, row=(lane>>4)*4+reg (gfx950-verified)
    const int ecol = lane & 15;
    const int q4   = (lane >> 4) * 4;
    #pragma unroll
    for (int m = 0; m < 4; ++m) {
        #pragma unroll
        for (int n = 0; n < 4; ++n) {
            const int gcol = colBase + wc + n * 16 + ecol;
            #pragma unroll
            for (int r = 0; r < 4; ++r) {
                const int grow = rowBase + wr + m * 16 + q4 + r;
                float v = acc[m][n][r];
                if (EPI == 0) {
                    ((half_t*)Cv)[z * bsC + (long long)grow * ldc + gcol] = (half_t)v;
                } else if (EPI == 1) {
                    ((float*)Cv)[(long long)grow * ldc + gcol] = v + bias[gcol];
                } else {
                    // QKV routing: block-uniform on colBase (128-col block
                    // lies entirely inside one of q/k/v's 1024-col spans)
                    const int mat = colBase >> 10;      // 0=q, 1=k, 2=v
                    const int c   = gcol & 1023;
                    if (mat == 0) {
                        ((half_t*)Cv)[(long long)grow * 1024 + c] = (half_t)(v * 0.03125f);
                    } else if (mat == 1) {
                        ((half_t*)C2)[(long long)grow * 1024 + c] = (half_t)v;
                    } else {
                        // vT[b][c][t], b=grow>>11, t=grow&2047
                        const long long bb = grow >> 11;
                        const long long tt = grow & 2047;
                        ((half_t*)C3)[bb * (1024LL * 2048) + (long long)c * 2048 + tt] = (half_t)v;
                    }
                }
            }
        }
    }
}

// fp32 -> fp16 flat cast, 8 elems/thread
__global__ __launch_bounds__(256)
void cast16(const float* __restrict__ x, half_t* __restrict__ y)
{
    const long long i = ((long long)blockIdx.x * 256 + threadIdx.x) * 8;
    floatx4 a = *(const floatx4*)(x + i);
    floatx4 b = *(const floatx4*)(x + i + 4);
    half8 h;
    #pragma unroll
    for (int j = 0; j < 4; ++j) { h[j] = (half_t)a[j]; h[j + 4] = (half_t)b[j]; }
    *(half8*)(y + i) = h;
}

// 1024x1024 fp32 -> fp16 transposed; grid.z selects which weight
__global__ __launch_bounds__(256)
void cast_transpose4(const float* __restrict__ W0, const float* __restrict__ W1,
                     const float* __restrict__ W2, const float* __restrict__ W3,
                     half_t* __restrict__ WT)
{
    const float* W = (blockIdx.z == 0) ? W0 : (blockIdx.z == 1) ? W1
                   : (blockIdx.z == 2) ? W2 : W3;
    half_t* O = WT + (long long)blockIdx.z * 1024 * 1024;
    __shared__ float t[32][33];
    const int bx = blockIdx.x * 32, by = blockIdx.y * 32;
    const int tx = threadIdx.x, ty = threadIdx.y;
    #pragma unroll
    for (int i = 0; i < 32; i += 8)
        t[ty + i][tx] = W[(long long)(by + ty + i) * 1024 + bx + tx];
    __syncthreads();
    #pragma unroll
    for (int i = 0; i < 32; i += 8)
        O[(long long)(bx + ty + i) * 1024 + by + tx] = (half_t)t[tx][ty + i];
}

// in-place fp16 row softmax over 2048; one 256-thr block per row; half8 I/O
__global__ __launch_bounds__(256)
void softmax_rows(half_t* __restrict__ S)
{
    const long long base = (long long)blockIdx.x * 2048;
    const int t = threadIdx.x;
    half8 h = *(const half8*)(S + base + t * 8);
    float v[8];
    #pragma unroll
    for (int i = 0; i < 8; ++i) v[i] = (float)h[i];
    float m = -3.0e38f;
    #pragma unroll
    for (int i = 0; i < 8; ++i) m = fmaxf(m, v[i]);
    #pragma unroll
    for (int off = 32; off > 0; off >>= 1) m = fmaxf(m, __shfl_down(m, off));
    __shared__ float redm[4], reds[4];
    const int lane = t & 63, wid = t >> 6;
    if (lane == 0) redm[wid] = m;
    __syncthreads();
    const float M = fmaxf(fmaxf(redm[0], redm[1]), fmaxf(redm[2], redm[3]));
    float s = 0.f;
    #pragma unroll
    for (int i = 0; i < 8; ++i) { v[i] = __expf(v[i] - M); s += v[i]; }
    #pragma unroll
    for (int off = 32; off > 0; off >>= 1) s += __shfl_down(s, off);
    if (lane == 0) reds[wid] = s;
    __syncthreads();
    const float inv = 1.0f / (reds[0] + reds[1] + reds[2] + reds[3]);
    #pragma unroll
    for (int i = 0; i < 8; ++i) h[i] = (half_t)(v[i] * inv);
    *(half8*)(S + base + t * 8) = h;
}

extern "C" void kernel_launch(void* const* d_in, const int* in_sizes, int n_in,
                              void* d_out, int out_size, void* d_ws, size_t ws_size,
                              hipStream_t stream)
{
    const float* x  = (const float*)d_in[0];
    const float* Wq = (const float*)d_in[1];
    const float* Wk = (const float*)d_in[2];
    const float* Wv = (const float*)d_in[3];
    const float* Wp = (const float*)d_in[4];
    const float* bp = (const float*)d_in[5];
    float* out = (float*)d_out;

    char* ws = (char*)d_ws;
    const long long MB = 1024LL * 1024LL;
    half_t* WqkvT = (half_t*)(ws + 0 * MB);   // [3072][1024] = WqT|WkT|WvT
    half_t* WpT   = (half_t*)(ws + 6 * MB);
    half_t* q     = (half_t*)(ws + 8 * MB);   // [8][2048][1024]; later ctx
    half_t* k     = (half_t*)(ws + 40 * MB);
    half_t* vT    = (half_t*)(ws + 72 * MB);  // [8][1024][2048]
    half_t* x16   = (half_t*)(ws + 104 * MB); // dead after QKV
    half_t* S     = (half_t*)(ws + 104 * MB); // [8][2048][2048] fp16, overlays x16

    dim3 blk(256);
    cast16<<<8192, blk, 0, stream>>>(x, x16);
    cast_transpose4<<<dim3(32, 32, 4), dim3(32, 8), 0, stream>>>(Wq, Wk, Wv, Wp, WqkvT);

    // fused QKV: [16384,1024] @ [3072,1024]^T, routed epilogue. 3072 blocks.
    gemm16<2><<<dim3(24, 128, 1), blk, 0, stream>>>(
        x16, WqkvT, q, k, vT, nullptr, 1024, 1024, 1024, 0, 0, 0, 0);

    // S = q @ k^T (fp16 out), all 8 batches. 2048 blocks (1 batch per XCD).
    gemm16<0><<<dim3(16, 16, 8), blk, 0, stream>>>(
        q, k, S, nullptr, nullptr, nullptr, 1024, 1024, 1024, 2048,
        2048LL * 1024, 2048LL * 1024, 2048LL * 2048);

    // P = softmax(S) in place
    softmax_rows<<<8 * 2048, blk, 0, stream>>>(S);

    // ctx = P @ vT^T (fp16), overwrites q. 1024 blocks.
    gemm16<0><<<dim3(8, 16, 8), blk, 0, stream>>>(
        S, vT, q, nullptr, nullptr, nullptr, 2048, 2048, 2048, 1024,
        2048LL * 2048, 1024LL * 2048, 2048LL * 1024);

    // out = ctx @ WpT^T + bp (fp32). 1024 blocks.
    gemm16<1><<<dim3(8, 128, 1), blk, 0, stream>>>(
        q, WpT, out, nullptr, nullptr, bp, 1024, 1024, 1024, 1024, 0, 0, 0);
}